// Round 14
// baseline (195.548 us; speedup 1.0000x reference)
//
#include <hip/hip_runtime.h>

#define B_  2
#define S_  2048
#define D_  1024
#define H_  16
#define DH_ 64
#define NDH (H_*DH_)   // 1024
#define BS_ (B_*S_)    // 4096
#define PER ((size_t)B_*H_*S_*DH_)   // 4M elements

typedef __bf16 bf16;
typedef bf16 bf16x8 __attribute__((ext_vector_type(8)));
typedef bf16 bf16x4 __attribute__((ext_vector_type(4)));
typedef float f32x4 __attribute__((ext_vector_type(4)));

// softmax scale folded into Q: 0.125 * log2(e); flash kernel then uses exp2
#define QSCALE 0.18033688011112042f

#define AS1 __attribute__((address_space(1)))
#define AS3 __attribute__((address_space(3)))
__device__ inline void gld16(const bf16* g, bf16* l) {
    __builtin_amdgcn_global_load_lds((const AS1 void*)g, (AS3 void*)l, 16, 0, 0);
}

// ---------------- fused prep: cast x -> bf16  +  transpose-cast 4 weight mats ----------------
__global__ __launch_bounds__(256) void prep(
        const float* __restrict__ x,
        const float* __restrict__ W0, const float* __restrict__ W1,
        const float* __restrict__ W2, const float* __restrict__ W3,
        bf16* __restrict__ xb, bf16* __restrict__ T0, bf16* __restrict__ T1,
        bf16* __restrict__ T2, bf16* __restrict__ T3) {
    __shared__ float T[32][33];
    int bid = blockIdx.x, t = threadIdx.x;
    if (bid < 4096) {
        int i = (bid * 256 + t) * 4;
        float4 v = *(const float4*)(x + i);
        bf16x4 o = { (bf16)v.x, (bf16)v.y, (bf16)v.z, (bf16)v.w };
        *(bf16x4*)(xb + i) = o;
        return;
    }
    int r2 = bid - 4096;
    int z = r2 >> 10, w = r2 & 1023;
    const float* W = (z == 0) ? W0 : (z == 1) ? W1 : (z == 2) ? W2 : W3;
    bf16* Wt = (z == 0) ? T0 : (z == 1) ? T1 : (z == 2) ? T2 : T3;
    int k0 = (w >> 5) * 32, n0 = (w & 31) * 32;
    int r = t >> 3, c = (t & 7) * 4;
    float4 v = *(const float4*)(W + (size_t)(k0 + r) * 1024 + n0 + c);
    T[c + 0][r] = v.x; T[c + 1][r] = v.y; T[c + 2][r] = v.z; T[c + 3][r] = v.w;
    __syncthreads();
    bf16x4 o = { (bf16)T[r][c], (bf16)T[r][c + 1], (bf16)T[r][c + 2], (bf16)T[r][c + 3] };
    *(bf16x4*)(Wt + (size_t)(n0 + r) * 1024 + k0 + c) = o;
}

// ---------------- fused QKV GEMM v3: 256x256 tile, BK=64, 8 waves, phase-scheduled ----------------
// Exit from the m97-structure ceiling (measured: 16 MFMA between barriers -> 3.5x overhead).
// 512 thr = 8 waves (2M x 4N), per-wave output 128x64 (acc[8][4]); 2-deep K-tile LDS buffers
// ([256][64] per matrix, 128 KB total). Per K-tile: 4 phases of {staging sweeps || 12 ds_read ||
// 16 MFMA (one C-quadrant x K=64) wrapped in setprio}; ONE vmcnt(0)+s_barrier per K-tile
// (64 MFMA between syncs). Stores for kt+1 issued phases 0-1, drained at tile end (~1200 cyc
// later -> hidden). Buffer invariant: buf^1 staged during kt was last READ in kt-1, protected
// by kt-1's boundary barrier.
// Bank conflicts: 128B-row tile + flash10-verified swizzle pair (source chunk ^= row&7, read
// chunk ^= l16&7) -> 2-way (free). (64B-row tiles are structurally >=8-way: only 3 span bits.)
__global__ __launch_bounds__(512) void qkv_gemm8(
        const bf16* __restrict__ A, const bf16* __restrict__ Bt,
        const float* __restrict__ bq, const float* __restrict__ bk,
        const float* __restrict__ bv, bf16* __restrict__ Qout, bf16* __restrict__ Vt) {
    __shared__ __align__(16) bf16 As[2][256 * 64];   // 64 KB
    __shared__ __align__(16) bf16 Bs[2][256 * 64];   // 64 KB
    int tid = threadIdx.x, wave = tid >> 6, lane = tid & 63;
    int quad = lane >> 4, l16 = lane & 15, lm = l16 & 7;
    int wr = wave >> 2, wc = wave & 3;

    int flat = blockIdx.y * 12 + blockIdx.x;          // nwg = 192
    int swz  = (flat & 7) * 24 + (flat >> 3);         // bijective: 192/8 = 24
    int bm = (swz / 12) * 256, bn = (swz % 12) * 256;

    // staging: thread covers LDS chunk (row = sweep*64 + wave*8 + (lane>>3), c = lane&7);
    // source chunk pre-XORed with row&7 (== lane>>3 here) so swizzled reads return true data.
    int r8 = lane >> 3, c8 = lane & 7;
    int scx = (c8 ^ r8) * 8;

    const bf16* Agb = A + (size_t)bm * 1024;
    const bf16* Bgb = Bt + (size_t)bn * 1024;

    f32x4 acc[8][4] = {};

    auto stageA = [&](int b, int kt) {   // 4 sweeps x 1 gld16
        int k0 = kt * 64;
        #pragma unroll
        for (int s = 0; s < 4; ++s) {
            int row = s * 64 + wave * 8;                       // wave-uniform
            gld16(Agb + (size_t)(row + r8) * 1024 + k0 + scx, &As[b][row * 64]);
        }
    };
    auto stageB = [&](int b, int kt) {
        int k0 = kt * 64;
        #pragma unroll
        for (int s = 0; s < 4; ++s) {
            int row = s * 64 + wave * 8;
            gld16(Bgb + (size_t)(row + r8) * 1024 + k0 + scx, &Bs[b][row * 64]);
        }
    };

    stageA(0, 0); stageB(0, 0);
    asm volatile("s_waitcnt vmcnt(0)" ::: "memory");
    __builtin_amdgcn_s_barrier();

    for (int kt = 0; kt < 16; ++kt) {
        int b = kt & 1;
        #pragma unroll
        for (int p = 0; p < 4; ++p) {
            if (p == 0 && kt + 1 < 16) stageA(b ^ 1, kt + 1);
            if (p == 1 && kt + 1 < 16) stageB(b ^ 1, kt + 1);
            const int mh = p >> 1, nh = p & 1;

            bf16x8 af[4][2], bfr[2][2];
            #pragma unroll
            for (int i = 0; i < 4; ++i) {
                int row = wr * 128 + (mh * 4 + i) * 16 + l16;
                #pragma unroll
                for (int ks = 0; ks < 2; ++ks)
                    af[i][ks] = *(const bf16x8*)&As[b][row * 64 + ((ks * 4 + quad) ^ lm) * 8];
            }
            #pragma unroll
            for (int j = 0; j < 2; ++j) {
                int row = wc * 64 + (nh * 2 + j) * 16 + l16;
                #pragma unroll
                for (int ks = 0; ks < 2; ++ks)
                    bfr[j][ks] = *(const bf16x8*)&Bs[b][row * 64 + ((ks * 4 + quad) ^ lm) * 8];
            }

            __builtin_amdgcn_s_setprio(1);
            #pragma unroll
            for (int i = 0; i < 4; ++i)
              #pragma unroll
              for (int j = 0; j < 2; ++j) {
                acc[mh * 4 + i][nh * 2 + j] = __builtin_amdgcn_mfma_f32_16x16x32_bf16(
                    af[i][0], bfr[j][0], acc[mh * 4 + i][nh * 2 + j], 0, 0, 0);
                acc[mh * 4 + i][nh * 2 + j] = __builtin_amdgcn_mfma_f32_16x16x32_bf16(
                    af[i][1], bfr[j][1], acc[mh * 4 + i][nh * 2 + j], 0, 0, 0);
              }
            __builtin_amdgcn_s_setprio(0);
        }
        asm volatile("s_waitcnt vmcnt(0)" ::: "memory");
        __builtin_amdgcn_s_barrier();
    }

    #pragma unroll
    for (int i = 0; i < 8; ++i)
      #pragma unroll
      for (int j = 0; j < 4; ++j) {
        int col = bn + wc * 64 + j * 16 + l16;
        float bias = (col < 1024) ? bq[col] : (col < 2048) ? bk[col - 1024] : bv[col - 2048];
        int qkv = col >> 10, cw = col & 1023;
        int hh = cw >> 6, d = cw & 63;
        int row0 = bm + wr * 128 + i * 16 + quad * 4;
        int bb = row0 >> 11, s0 = row0 & 2047;
        if (qkv < 2) {
            float scl = (qkv == 0) ? QSCALE : 1.0f;
            #pragma unroll
            for (int r = 0; r < 4; ++r)
                Qout[(size_t)qkv * PER + (((size_t)bb * H_ + hh) * S_ + s0 + r) * DH_ + d] =
                    (bf16)((acc[i][j][r] + bias) * scl);
        } else {
            bf16x4 pack;
            #pragma unroll
            for (int r = 0; r < 4; ++r) pack[r] = (bf16)(acc[i][j][r] + bias);
            *(bf16x4*)&Vt[(((size_t)bb * H_ + hh) * DH_ + d) * S_ + s0] = pack;
        }
      }
}

// ---------------- output-projection GEMM v2 (round-8): 128x64, 3-buffer + counted vmcnt ----------------
__global__ __launch_bounds__(256) void gemm_proj(
        const bf16* __restrict__ A, const bf16* __restrict__ Bt,
        const float* __restrict__ bias, float* __restrict__ out) {
    __shared__ __align__(16) bf16 As[3][128 * 32];   // 24 KB
    __shared__ __align__(16) bf16 Bs[3][64 * 32];    // 12 KB
    int tid = threadIdx.x, wave = tid >> 6, lane = tid & 63;
    int quad = lane >> 4, l16 = lane & 15;

    int flat = blockIdx.y * 16 + blockIdx.x;          // nwg = 512
    int swz  = (flat & 7) * 64 + (flat >> 3);         // bijective: 512/8 = 64
    int bm = (swz / 16) * 128, bn = (swz % 16) * 64;
    int wm = (wave >> 1) * 64, wn = (wave & 1) * 32;

    int sr = lane >> 2;
    int sc = (((lane & 3) ^ ((sr ^ (sr >> 2)) & 3)) * 8);
    const bf16* Ag0 = A + (size_t)(bm + (wave * 2 + 0) * 16 + sr) * 1024 + sc;
    const bf16* Ag1 = A + (size_t)(bm + (wave * 2 + 1) * 16 + sr) * 1024 + sc;
    const bf16* Bg0 = Bt + (size_t)(bn + wave * 16 + sr) * 1024 + sc;
    int la0 = (wave * 2 + 0) * 512;
    int la1 = (wave * 2 + 1) * 512;
    int lb0 = wave * 512;

    int rsw = (l16 ^ (l16 >> 2)) & 3;

    f32x4 acc[4][2] = {};

    auto stage = [&](int buf, int t) {
        int k0 = t * 32;
        gld16(Ag0 + k0, &As[buf][la0]);
        gld16(Ag1 + k0, &As[buf][la1]);
        gld16(Bg0 + k0, &Bs[buf][lb0]);
    };

    stage(0, 0);
    stage(1, 1);

    for (int t = 0; t < 32; ++t) {
        if (t < 30) asm volatile("s_waitcnt vmcnt(3)" ::: "memory");
        else        asm volatile("s_waitcnt vmcnt(0)" ::: "memory");
        __builtin_amdgcn_s_barrier();
        if (t + 2 < 32) stage((t + 2) % 3, t + 2);
        int cur = t % 3;
        bf16x8 af[4], bfr[2];
        #pragma unroll
        for (int i = 0; i < 4; ++i)
            af[i] = *(const bf16x8*)&As[cur][(wm + i * 16 + l16) * 32 + (quad ^ rsw) * 8];
        #pragma unroll
        for (int j = 0; j < 2; ++j)
            bfr[j] = *(const bf16x8*)&Bs[cur][(wn + j * 16 + l16) * 32 + (quad ^ rsw) * 8];
        #pragma unroll
        for (int i = 0; i < 4; ++i)
          #pragma unroll
          for (int j = 0; j < 2; ++j)
            acc[i][j] = __builtin_amdgcn_mfma_f32_16x16x32_bf16(af[i], bfr[j], acc[i][j], 0, 0, 0);
    }
    __builtin_amdgcn_s_barrier();

    #pragma unroll
    for (int i = 0; i < 4; ++i)
      #pragma unroll
      for (int j = 0; j < 2; ++j) {
        int col = bn + wn + j * 16 + l16;
        float b = bias[col];
        #pragma unroll
        for (int r = 0; r < 4; ++r) {
            int row = bm + wm + i * 16 + quad * 4 + r;
            out[(size_t)row * 1024 + col] = acc[i][j][r] + b;
        }
      }
}

// ---------------- flash attention v15 (round-13 champion): swapped QK^T, packed b64 P-stores ----------------
__global__ __launch_bounds__(256) void flash15(
        const bf16* __restrict__ Q, const bf16* __restrict__ K,
        const bf16* __restrict__ Vt, bf16* __restrict__ O) {
    int bh = blockIdx.x;
    int b = bh >> 4, h = bh & 15;
    int t = 31 - blockIdx.y;             // heavy tiles dispatch first
    int q0 = t * 64;
    int nkt = t + 1;
    int tid = threadIdx.x;
    int wave = tid >> 6, lane = tid & 63;
    int quad = lane >> 4, l16 = lane & 15;
    int lm = l16 & 7;

    __shared__ __align__(16) bf16 Kl[2][64 * 64];   // 16 KB
    __shared__ __align__(16) bf16 Vl[2][64 * 64];   // 16 KB
    __shared__ bf16 P[4][16][72];                   // 9 KB, per-wave private

    const bf16* Qb = Q + (size_t)bh * S_ * DH_;
    const bf16* Kb = K + (size_t)bh * S_ * DH_;
    const bf16* Vb = Vt + (size_t)bh * DH_ * S_;

    bf16x8 qf[2];
    {
        const bf16* qp = Qb + (size_t)(q0 + wave * 16 + l16) * DH_ + quad * 8;
        qf[0] = *(const bf16x8*)(qp);
        qf[1] = *(const bf16x8*)(qp + 32);
    }

    bf16x8 ones;
    #pragma unroll
    for (int j = 0; j < 8; ++j) ones[j] = (l16 == 0) ? (bf16)1.0f : (bf16)0.0f;

    f32x4 oacc[4] = {};
    f32x4 lacc = {};

    int r8 = lane >> 3, c8 = lane & 7;
    int sco = ((c8 ^ r8) * 8);

    auto stage = [&](int buf, int kt) {
        int kv0 = kt * 64;
        #pragma unroll
        for (int g = 0; g < 2; ++g) {
            int row = wave * 16 + g * 8;                       // wave-uniform
            gld16(Kb + (size_t)(kv0 + row + r8) * DH_ + sco, &Kl[buf][row * 64]);
            gld16(Vb + (size_t)(row + r8) * S_ + kv0 + sco,   &Vl[buf][row * 64]);
        }
    };

    stage(0, 0);
    __syncthreads();     // buffer 0 ready

    for (int kt = 0; kt < nkt; ++kt) {
        int buf = kt & 1;
        if (kt + 1 < nkt) stage(buf ^ 1, kt + 1);   // async prefetch next chunk
        int kv0 = kt * 64;

        bf16x8 kf[4][2];
        #pragma unroll
        for (int ns = 0; ns < 4; ++ns) {
            int row = ns * 16 + l16;
            kf[ns][0] = *(const bf16x8*)&Kl[buf][row * 64 + ((quad)     ^ lm) * 8];
            kf[ns][1] = *(const bf16x8*)&Kl[buf][row * 64 + ((4 + quad) ^ lm) * 8];
        }

        // swapped QK^T (flash6-verified): sacc[ns][r] = S[q=l16][kv=kv0+ns*16+quad*4+r]
        f32x4 sacc[4] = {};
        #pragma unroll
        for (int ns = 0; ns < 4; ++ns) {
            sacc[ns] = __builtin_amdgcn_mfma_f32_16x16x32_bf16(kf[ns][0], qf[0], sacc[ns], 0, 0, 0);
            sacc[ns] = __builtin_amdgcn_mfma_f32_16x16x32_bf16(kf[ns][1], qf[1], sacc[ns], 0, 0, 0);
        }

        bool diag = (kt == nkt - 1);
        #pragma unroll
        for (int ns = 0; ns < 4; ++ns) {
            bf16x4 pk;
            #pragma unroll
            for (int r = 0; r < 4; ++r) {
                float p = __builtin_amdgcn_exp2f(sacc[ns][r]);
                if (diag) {
                    int kv = kv0 + ns * 16 + quad * 4 + r;
                    int qq = q0 + wave * 16 + l16;
                    if (kv > qq) p = 0.f;
                }
                pk[r] = (bf16)p;
            }
            *(bf16x4*)&P[wave][l16][ns * 16 + quad * 4] = pk;
        }

        #pragma unroll
        for (int ks = 0; ks < 2; ++ks) {
            bf16x8 pf = *(const bf16x8*)&P[wave][l16][ks * 32 + quad * 8];
            lacc = __builtin_amdgcn_mfma_f32_16x16x32_bf16(pf, ones, lacc, 0, 0, 0);
            #pragma unroll
            for (int ds = 0; ds < 4; ++ds) {
                bf16x8 vf = *(const bf16x8*)&Vl[buf][(ds * 16 + l16) * 64 + ((ks * 4 + quad) ^ lm) * 8];
                oacc[ds] = __builtin_amdgcn_mfma_f32_16x16x32_bf16(pf, vf, oacc[ds], 0, 0, 0);
            }
        }

        __syncthreads();   // next buffer staged (vmcnt drained) + all waves done with buf
    }

    float ls[4];
    #pragma unroll
    for (int r = 0; r < 4; ++r) ls[r] = __shfl(lacc[r], quad << 4);
    #pragma unroll
    for (int ds = 0; ds < 4; ++ds)
      #pragma unroll
      for (int r = 0; r < 4; ++r) {
          int qq = q0 + wave * 16 + quad * 4 + r;
          O[((size_t)b * S_ + qq) * NDH + h * DH_ + ds * 16 + l16] = (bf16)(oacc[ds][r] / ls[r]);
      }
}

extern "C" void kernel_launch(void* const* d_in, const int* in_sizes, int n_in,
                              void* d_out, int out_size, void* d_ws, size_t ws_size,
                              hipStream_t stream) {
    const float* x  = (const float*)d_in[0];
    const float* Wq = (const float*)d_in[1];
    const float* bq = (const float*)d_in[2];
    const float* Wk = (const float*)d_in[3];
    const float* bk = (const float*)d_in[4];
    const float* Wv = (const float*)d_in[5];
    const float* bv = (const float*)d_in[6];
    const float* Wo = (const float*)d_in[7];
    const float* bo = (const float*)d_in[8];
    float* out = (float*)d_out;

    bf16* ws = (bf16*)d_ws;
    const size_t M1 = (size_t)1024 * 1024;
    bf16* xb    = ws;                   // 4M
    bf16* WqkvT = ws + 4 * M1;          // 3M contiguous (WqT|WkT|WvT)
    bf16* WoT   = ws + 7 * M1;          // 1M
    bf16* Qw    = ws + 8 * M1;          // Q|K contiguous, 4M each
    bf16* Vtw   = ws + 16 * M1;         // 4M ([bh][d][s])
    bf16* Ow    = ws + 20 * M1;         // 4M

    prep<<<8192, 256, 0, stream>>>(x, Wq, Wk, Wv, Wo,
                                   xb, WqkvT, WqkvT + M1, WqkvT + 2 * M1, WoT);

    qkv_gemm8<<<dim3(12, 16), 512, 0, stream>>>(xb, WqkvT, bq, bk, bv, Qw, Vtw);

    flash15<<<dim3(B_ * H_, 32), 256, 0, stream>>>(Qw, Qw + PER, Vtw, Ow);

    gemm_proj<<<dim3(1024 / 64, BS_ / 128), 256, 0, stream>>>(Ow, WoT, bo, out);
}

// Round 15
// 181.363 us; speedup vs baseline: 1.0782x; 1.0782x over previous
//
#include <hip/hip_runtime.h>

#define B_  2
#define S_  2048
#define D_  1024
#define H_  16
#define DH_ 64
#define NDH (H_*DH_)   // 1024
#define BS_ (B_*S_)    // 4096
#define PER ((size_t)B_*H_*S_*DH_)   // 4M elements

typedef __bf16 bf16;
typedef bf16 bf16x8 __attribute__((ext_vector_type(8)));
typedef bf16 bf16x4 __attribute__((ext_vector_type(4)));
typedef float f32x4 __attribute__((ext_vector_type(4)));

// softmax scale folded into Q: 0.125 * log2(e); flash kernel then uses exp2
#define QSCALE 0.18033688011112042f

#define AS1 __attribute__((address_space(1)))
#define AS3 __attribute__((address_space(3)))
__device__ inline void gld16(const bf16* g, bf16* l) {
    __builtin_amdgcn_global_load_lds((const AS1 void*)g, (AS3 void*)l, 16, 0, 0);
}

// ---------------- fused prep: cast x -> bf16  +  transpose-cast 4 weight mats ----------------
__global__ __launch_bounds__(256) void prep(
        const float* __restrict__ x,
        const float* __restrict__ W0, const float* __restrict__ W1,
        const float* __restrict__ W2, const float* __restrict__ W3,
        bf16* __restrict__ xb, bf16* __restrict__ T0, bf16* __restrict__ T1,
        bf16* __restrict__ T2, bf16* __restrict__ T3) {
    __shared__ float T[32][33];
    int bid = blockIdx.x, t = threadIdx.x;
    if (bid < 4096) {
        int i = (bid * 256 + t) * 4;
        float4 v = *(const float4*)(x + i);
        bf16x4 o = { (bf16)v.x, (bf16)v.y, (bf16)v.z, (bf16)v.w };
        *(bf16x4*)(xb + i) = o;
        return;
    }
    int r2 = bid - 4096;
    int z = r2 >> 10, w = r2 & 1023;
    const float* W = (z == 0) ? W0 : (z == 1) ? W1 : (z == 2) ? W2 : W3;
    bf16* Wt = (z == 0) ? T0 : (z == 1) ? T1 : (z == 2) ? T2 : T3;
    int k0 = (w >> 5) * 32, n0 = (w & 31) * 32;
    int r = t >> 3, c = (t & 7) * 4;
    float4 v = *(const float4*)(W + (size_t)(k0 + r) * 1024 + n0 + c);
    T[c + 0][r] = v.x; T[c + 1][r] = v.y; T[c + 2][r] = v.z; T[c + 3][r] = v.w;
    __syncthreads();
    bf16x4 o = { (bf16)T[r][c], (bf16)T[r][c + 1], (bf16)T[r][c + 2], (bf16)T[r][c + 3] };
    *(bf16x4*)(Wt + (size_t)(n0 + r) * 1024 + k0 + c) = o;
}

// ---------------- fused QKV GEMM v2 (round-8 champion): 3-buffer + counted vmcnt ----------------
__global__ __launch_bounds__(256) void qkv_gemm(
        const bf16* __restrict__ A, const bf16* __restrict__ Bt,
        const float* __restrict__ bq, const float* __restrict__ bk,
        const float* __restrict__ bv, bf16* __restrict__ Qout, bf16* __restrict__ Vt) {
    __shared__ __align__(16) bf16 As[3][128 * 32];   // 24 KB
    __shared__ __align__(16) bf16 Bs[3][128 * 32];   // 24 KB
    int tid = threadIdx.x, wave = tid >> 6, lane = tid & 63;
    int quad = lane >> 4, l16 = lane & 15;

    int flat = blockIdx.y * 24 + blockIdx.x;          // nwg = 768
    int swz  = (flat & 7) * 96 + (flat >> 3);         // bijective: 768/8 = 96
    int bm = (swz / 24) * 128, bn = (swz % 24) * 128;
    int wm = (wave >> 1) * 64, wn = (wave & 1) * 64;

    int sr = lane >> 2;
    int sc = (((lane & 3) ^ ((sr ^ (sr >> 2)) & 3)) * 8);
    const bf16* Ag0 = A + (size_t)(bm + (wave * 2 + 0) * 16 + sr) * 1024 + sc;
    const bf16* Ag1 = A + (size_t)(bm + (wave * 2 + 1) * 16 + sr) * 1024 + sc;
    const bf16* Bg0 = Bt + (size_t)(bn + (wave * 2 + 0) * 16 + sr) * 1024 + sc;
    const bf16* Bg1 = Bt + (size_t)(bn + (wave * 2 + 1) * 16 + sr) * 1024 + sc;
    int la0 = (wave * 2 + 0) * 512;
    int la1 = (wave * 2 + 1) * 512;

    int rsw = (l16 ^ (l16 >> 2)) & 3;

    f32x4 acc[4][4] = {};

    auto stage = [&](int buf, int t) {
        int k0 = t * 32;
        gld16(Ag0 + k0, &As[buf][la0]);
        gld16(Ag1 + k0, &As[buf][la1]);
        gld16(Bg0 + k0, &Bs[buf][la0]);
        gld16(Bg1 + k0, &Bs[buf][la1]);
    };

    stage(0, 0);
    stage(1, 1);

    for (int t = 0; t < 32; ++t) {
        if (t < 30) asm volatile("s_waitcnt vmcnt(4)" ::: "memory");
        else        asm volatile("s_waitcnt vmcnt(0)" ::: "memory");
        __builtin_amdgcn_s_barrier();
        if (t + 2 < 32) stage((t + 2) % 3, t + 2);
        int cur = t % 3;
        bf16x8 af[4], bfr[4];
        #pragma unroll
        for (int i = 0; i < 4; ++i)
            af[i] = *(const bf16x8*)&As[cur][(wm + i * 16 + l16) * 32 + (quad ^ rsw) * 8];
        #pragma unroll
        for (int j = 0; j < 4; ++j)
            bfr[j] = *(const bf16x8*)&Bs[cur][(wn + j * 16 + l16) * 32 + (quad ^ rsw) * 8];
        #pragma unroll
        for (int i = 0; i < 4; ++i)
          #pragma unroll
          for (int j = 0; j < 4; ++j)
            acc[i][j] = __builtin_amdgcn_mfma_f32_16x16x32_bf16(af[i], bfr[j], acc[i][j], 0, 0, 0);
    }
    __builtin_amdgcn_s_barrier();

    #pragma unroll
    for (int i = 0; i < 4; ++i)
      #pragma unroll
      for (int j = 0; j < 4; ++j) {
        int col = bn + wn + j * 16 + l16;
        float bias = (col < 1024) ? bq[col] : (col < 2048) ? bk[col - 1024] : bv[col - 2048];
        int qkv = col >> 10, cw = col & 1023;
        int hh = cw >> 6, d = cw & 63;
        int row0 = bm + wm + i * 16 + quad * 4;
        int bb = row0 >> 11, s0 = row0 & 2047;
        if (qkv < 2) {
            float scl = (qkv == 0) ? QSCALE : 1.0f;
            #pragma unroll
            for (int r = 0; r < 4; ++r)
                Qout[(size_t)qkv * PER + (((size_t)bb * H_ + hh) * S_ + s0 + r) * DH_ + d] =
                    (bf16)((acc[i][j][r] + bias) * scl);
        } else {
            bf16x4 pack;
            #pragma unroll
            for (int r = 0; r < 4; ++r) pack[r] = (bf16)(acc[i][j][r] + bias);
            *(bf16x4*)&Vt[(((size_t)bb * H_ + hh) * DH_ + d) * S_ + s0] = pack;
        }
      }
}

// ---------------- output-projection GEMM v2 (round-8): 128x64, 3-buffer + counted vmcnt ----------------
__global__ __launch_bounds__(256) void gemm_proj(
        const bf16* __restrict__ A, const bf16* __restrict__ Bt,
        const float* __restrict__ bias, float* __restrict__ out) {
    __shared__ __align__(16) bf16 As[3][128 * 32];   // 24 KB
    __shared__ __align__(16) bf16 Bs[3][64 * 32];    // 12 KB
    int tid = threadIdx.x, wave = tid >> 6, lane = tid & 63;
    int quad = lane >> 4, l16 = lane & 15;

    int flat = blockIdx.y * 16 + blockIdx.x;          // nwg = 512
    int swz  = (flat & 7) * 64 + (flat >> 3);         // bijective: 512/8 = 64
    int bm = (swz / 16) * 128, bn = (swz % 16) * 64;
    int wm = (wave >> 1) * 64, wn = (wave & 1) * 32;

    int sr = lane >> 2;
    int sc = (((lane & 3) ^ ((sr ^ (sr >> 2)) & 3)) * 8);
    const bf16* Ag0 = A + (size_t)(bm + (wave * 2 + 0) * 16 + sr) * 1024 + sc;
    const bf16* Ag1 = A + (size_t)(bm + (wave * 2 + 1) * 16 + sr) * 1024 + sc;
    const bf16* Bg0 = Bt + (size_t)(bn + wave * 16 + sr) * 1024 + sc;
    int la0 = (wave * 2 + 0) * 512;
    int la1 = (wave * 2 + 1) * 512;
    int lb0 = wave * 512;

    int rsw = (l16 ^ (l16 >> 2)) & 3;

    f32x4 acc[4][2] = {};

    auto stage = [&](int buf, int t) {
        int k0 = t * 32;
        gld16(Ag0 + k0, &As[buf][la0]);
        gld16(Ag1 + k0, &As[buf][la1]);
        gld16(Bg0 + k0, &Bs[buf][lb0]);
    };

    stage(0, 0);
    stage(1, 1);

    for (int t = 0; t < 32; ++t) {
        if (t < 30) asm volatile("s_waitcnt vmcnt(3)" ::: "memory");
        else        asm volatile("s_waitcnt vmcnt(0)" ::: "memory");
        __builtin_amdgcn_s_barrier();
        if (t + 2 < 32) stage((t + 2) % 3, t + 2);
        int cur = t % 3;
        bf16x8 af[4], bfr[2];
        #pragma unroll
        for (int i = 0; i < 4; ++i)
            af[i] = *(const bf16x8*)&As[cur][(wm + i * 16 + l16) * 32 + (quad ^ rsw) * 8];
        #pragma unroll
        for (int j = 0; j < 2; ++j)
            bfr[j] = *(const bf16x8*)&Bs[cur][(wn + j * 16 + l16) * 32 + (quad ^ rsw) * 8];
        #pragma unroll
        for (int i = 0; i < 4; ++i)
          #pragma unroll
          for (int j = 0; j < 2; ++j)
            acc[i][j] = __builtin_amdgcn_mfma_f32_16x16x32_bf16(af[i], bfr[j], acc[i][j], 0, 0, 0);
    }
    __builtin_amdgcn_s_barrier();

    #pragma unroll
    for (int i = 0; i < 4; ++i)
      #pragma unroll
      for (int j = 0; j < 2; ++j) {
        int col = bn + wn + j * 16 + l16;
        float b = bias[col];
        #pragma unroll
        for (int r = 0; r < 4; ++r) {
            int row = bm + wm + i * 16 + quad * 4 + r;
            out[(size_t)row * 1024 + col] = acc[i][j][r] + b;
        }
      }
}

// ---------------- flash attention v15 (round-13 champion): swapped QK^T, packed b64 P-stores ----------------
// Base = flash10 (round-7): 64-row q-tile, 4 waves x 16 q-rows, K+V staged into 2-buffer LDS via
// gld16 + source-swizzle, heavy-first grid, direct-O epilogue. Swapped QK (mfma(K,Q)) packs the
// P-scatter into 4 ds_write_b64 writing the same P[q][kv] layout the PV-read consumes.
__global__ __launch_bounds__(256) void flash15(
        const bf16* __restrict__ Q, const bf16* __restrict__ K,
        const bf16* __restrict__ Vt, bf16* __restrict__ O) {
    int bh = blockIdx.x;
    int b = bh >> 4, h = bh & 15;
    int t = 31 - blockIdx.y;             // heavy tiles dispatch first
    int q0 = t * 64;
    int nkt = t + 1;
    int tid = threadIdx.x;
    int wave = tid >> 6, lane = tid & 63;
    int quad = lane >> 4, l16 = lane & 15;
    int lm = l16 & 7;

    __shared__ __align__(16) bf16 Kl[2][64 * 64];   // 16 KB
    __shared__ __align__(16) bf16 Vl[2][64 * 64];   // 16 KB
    __shared__ bf16 P[4][16][72];                   // 9 KB, per-wave private

    const bf16* Qb = Q + (size_t)bh * S_ * DH_;
    const bf16* Kb = K + (size_t)bh * S_ * DH_;
    const bf16* Vb = Vt + (size_t)bh * DH_ * S_;

    bf16x8 qf[2];
    {
        const bf16* qp = Qb + (size_t)(q0 + wave * 16 + l16) * DH_ + quad * 8;
        qf[0] = *(const bf16x8*)(qp);
        qf[1] = *(const bf16x8*)(qp + 32);
    }

    bf16x8 ones;
    #pragma unroll
    for (int j = 0; j < 8; ++j) ones[j] = (l16 == 0) ? (bf16)1.0f : (bf16)0.0f;

    f32x4 oacc[4] = {};
    f32x4 lacc = {};

    int r8 = lane >> 3, c8 = lane & 7;
    int sco = ((c8 ^ r8) * 8);

    auto stage = [&](int buf, int kt) {
        int kv0 = kt * 64;
        #pragma unroll
        for (int g = 0; g < 2; ++g) {
            int row = wave * 16 + g * 8;                       // wave-uniform
            gld16(Kb + (size_t)(kv0 + row + r8) * DH_ + sco, &Kl[buf][row * 64]);
            gld16(Vb + (size_t)(row + r8) * S_ + kv0 + sco,   &Vl[buf][row * 64]);
        }
    };

    stage(0, 0);
    __syncthreads();     // buffer 0 ready

    for (int kt = 0; kt < nkt; ++kt) {
        int buf = kt & 1;
        if (kt + 1 < nkt) stage(buf ^ 1, kt + 1);   // async prefetch next chunk
        int kv0 = kt * 64;

        bf16x8 kf[4][2];
        #pragma unroll
        for (int ns = 0; ns < 4; ++ns) {
            int row = ns * 16 + l16;
            kf[ns][0] = *(const bf16x8*)&Kl[buf][row * 64 + ((quad)     ^ lm) * 8];
            kf[ns][1] = *(const bf16x8*)&Kl[buf][row * 64 + ((4 + quad) ^ lm) * 8];
        }

        // swapped QK^T (flash6-verified): sacc[ns][r] = S[q=l16][kv=kv0+ns*16+quad*4+r]
        f32x4 sacc[4] = {};
        #pragma unroll
        for (int ns = 0; ns < 4; ++ns) {
            sacc[ns] = __builtin_amdgcn_mfma_f32_16x16x32_bf16(kf[ns][0], qf[0], sacc[ns], 0, 0, 0);
            sacc[ns] = __builtin_amdgcn_mfma_f32_16x16x32_bf16(kf[ns][1], qf[1], sacc[ns], 0, 0, 0);
        }

        bool diag = (kt == nkt - 1);
        #pragma unroll
        for (int ns = 0; ns < 4; ++ns) {
            bf16x4 pk;
            #pragma unroll
            for (int r = 0; r < 4; ++r) {
                float p = __builtin_amdgcn_exp2f(sacc[ns][r]);
                if (diag) {
                    int kv = kv0 + ns * 16 + quad * 4 + r;
                    int qq = q0 + wave * 16 + l16;
                    if (kv > qq) p = 0.f;
                }
                pk[r] = (bf16)p;
            }
            *(bf16x4*)&P[wave][l16][ns * 16 + quad * 4] = pk;
        }

        #pragma unroll
        for (int ks = 0; ks < 2; ++ks) {
            bf16x8 pf = *(const bf16x8*)&P[wave][l16][ks * 32 + quad * 8];
            lacc = __builtin_amdgcn_mfma_f32_16x16x32_bf16(pf, ones, lacc, 0, 0, 0);
            #pragma unroll
            for (int ds = 0; ds < 4; ++ds) {
                bf16x8 vf = *(const bf16x8*)&Vl[buf][(ds * 16 + l16) * 64 + ((ks * 4 + quad) ^ lm) * 8];
                oacc[ds] = __builtin_amdgcn_mfma_f32_16x16x32_bf16(pf, vf, oacc[ds], 0, 0, 0);
            }
        }

        __syncthreads();   // next buffer staged (vmcnt drained) + all waves done with buf
    }

    float ls[4];
    #pragma unroll
    for (int r = 0; r < 4; ++r) ls[r] = __shfl(lacc[r], quad << 4);
    #pragma unroll
    for (int ds = 0; ds < 4; ++ds)
      #pragma unroll
      for (int r = 0; r < 4; ++r) {
          int qq = q0 + wave * 16 + quad * 4 + r;
          O[((size_t)b * S_ + qq) * NDH + h * DH_ + ds * 16 + l16] = (bf16)(oacc[ds][r] / ls[r]);
      }
}

extern "C" void kernel_launch(void* const* d_in, const int* in_sizes, int n_in,
                              void* d_out, int out_size, void* d_ws, size_t ws_size,
                              hipStream_t stream) {
    const float* x  = (const float*)d_in[0];
    const float* Wq = (const float*)d_in[1];
    const float* bq = (const float*)d_in[2];
    const float* Wk = (const float*)d_in[3];
    const float* bk = (const float*)d_in[4];
    const float* Wv = (const float*)d_in[5];
    const float* bv = (const float*)d_in[6];
    const float* Wo = (const float*)d_in[7];
    const float* bo = (const float*)d_in[8];
    float* out = (float*)d_out;

    bf16* ws = (bf16*)d_ws;
    const size_t M1 = (size_t)1024 * 1024;
    bf16* xb    = ws;                   // 4M
    bf16* WqkvT = ws + 4 * M1;          // 3M contiguous (WqT|WkT|WvT)
    bf16* WoT   = ws + 7 * M1;          // 1M
    bf16* Qw    = ws + 8 * M1;          // Q|K contiguous, 4M each
    bf16* Vtw   = ws + 16 * M1;         // 4M ([bh][d][s])
    bf16* Ow    = ws + 20 * M1;         // 4M

    prep<<<8192, 256, 0, stream>>>(x, Wq, Wk, Wv, Wo,
                                   xb, WqkvT, WqkvT + M1, WqkvT + 2 * M1, WoT);

    qkv_gemm<<<dim3(3072 / 128, BS_ / 128), 256, 0, stream>>>(xb, WqkvT, bq, bk, bv, Qw, Vtw);

    flash15<<<dim3(B_ * H_, 32), 256, 0, stream>>>(Qw, Qw + PER, Vtw, Ow);

    gemm_proj<<<dim3(1024 / 64, BS_ / 128), 256, 0, stream>>>(Ow, WoT, bo, out);
}

// Round 16
// 180.121 us; speedup vs baseline: 1.0856x; 1.0069x over previous
//
#include <hip/hip_runtime.h>

#define B_  2
#define S_  2048
#define D_  1024
#define H_  16
#define DH_ 64
#define NDH (H_*DH_)   // 1024
#define BS_ (B_*S_)    // 4096
#define PER ((size_t)B_*H_*S_*DH_)   // 4M elements

typedef __bf16 bf16;
typedef bf16 bf16x8 __attribute__((ext_vector_type(8)));
typedef bf16 bf16x4 __attribute__((ext_vector_type(4)));
typedef float f32x4 __attribute__((ext_vector_type(4)));

// softmax scale folded into Q: 0.125 * log2(e); flash kernel then uses exp2
#define QSCALE 0.18033688011112042f

#define AS1 __attribute__((address_space(1)))
#define AS3 __attribute__((address_space(3)))
__device__ inline void gld16(const bf16* g, bf16* l) {
    __builtin_amdgcn_global_load_lds((const AS1 void*)g, (AS3 void*)l, 16, 0, 0);
}

// ---------------- fused prep: cast x -> bf16 (16B/lane, G13)  +  transpose-cast 4 weight mats ----------------
// blocks [0,2048): cast 8 floats/thread; [2048, 6144): 4x transW (1024 blocks each, unchanged).
__global__ __launch_bounds__(256) void prep(
        const float* __restrict__ x,
        const float* __restrict__ W0, const float* __restrict__ W1,
        const float* __restrict__ W2, const float* __restrict__ W3,
        bf16* __restrict__ xb, bf16* __restrict__ T0, bf16* __restrict__ T1,
        bf16* __restrict__ T2, bf16* __restrict__ T3) {
    __shared__ float T[32][33];
    int bid = blockIdx.x, t = threadIdx.x;
    if (bid < 2048) {
        int i = (bid * 256 + t) * 8;
        float4 v0 = *(const float4*)(x + i);
        float4 v1 = *(const float4*)(x + i + 4);
        bf16x8 o = { (bf16)v0.x, (bf16)v0.y, (bf16)v0.z, (bf16)v0.w,
                     (bf16)v1.x, (bf16)v1.y, (bf16)v1.z, (bf16)v1.w };
        *(bf16x8*)(xb + i) = o;
        return;
    }
    int r2 = bid - 2048;
    int z = r2 >> 10, w = r2 & 1023;
    const float* W = (z == 0) ? W0 : (z == 1) ? W1 : (z == 2) ? W2 : W3;
    bf16* Wt = (z == 0) ? T0 : (z == 1) ? T1 : (z == 2) ? T2 : T3;
    int k0 = (w >> 5) * 32, n0 = (w & 31) * 32;
    int r = t >> 3, c = (t & 7) * 4;
    float4 v = *(const float4*)(W + (size_t)(k0 + r) * 1024 + n0 + c);
    T[c + 0][r] = v.x; T[c + 1][r] = v.y; T[c + 2][r] = v.z; T[c + 3][r] = v.w;
    __syncthreads();
    bf16x4 o = { (bf16)T[r][c], (bf16)T[r][c + 1], (bf16)T[r][c + 2], (bf16)T[r][c + 3] };
    *(bf16x4*)(Wt + (size_t)(n0 + r) * 1024 + k0 + c) = o;
}

// ---------------- fused QKV GEMM v2 (round-8 champion): 3-buffer + counted vmcnt ----------------
__global__ __launch_bounds__(256) void qkv_gemm(
        const bf16* __restrict__ A, const bf16* __restrict__ Bt,
        const float* __restrict__ bq, const float* __restrict__ bk,
        const float* __restrict__ bv, bf16* __restrict__ Qout, bf16* __restrict__ Vt) {
    __shared__ __align__(16) bf16 As[3][128 * 32];   // 24 KB
    __shared__ __align__(16) bf16 Bs[3][128 * 32];   // 24 KB
    int tid = threadIdx.x, wave = tid >> 6, lane = tid & 63;
    int quad = lane >> 4, l16 = lane & 15;

    int flat = blockIdx.y * 24 + blockIdx.x;          // nwg = 768
    int swz  = (flat & 7) * 96 + (flat >> 3);         // bijective: 768/8 = 96
    int bm = (swz / 24) * 128, bn = (swz % 24) * 128;
    int wm = (wave >> 1) * 64, wn = (wave & 1) * 64;

    int sr = lane >> 2;
    int sc = (((lane & 3) ^ ((sr ^ (sr >> 2)) & 3)) * 8);
    const bf16* Ag0 = A + (size_t)(bm + (wave * 2 + 0) * 16 + sr) * 1024 + sc;
    const bf16* Ag1 = A + (size_t)(bm + (wave * 2 + 1) * 16 + sr) * 1024 + sc;
    const bf16* Bg0 = Bt + (size_t)(bn + (wave * 2 + 0) * 16 + sr) * 1024 + sc;
    const bf16* Bg1 = Bt + (size_t)(bn + (wave * 2 + 1) * 16 + sr) * 1024 + sc;
    int la0 = (wave * 2 + 0) * 512;
    int la1 = (wave * 2 + 1) * 512;

    int rsw = (l16 ^ (l16 >> 2)) & 3;

    f32x4 acc[4][4] = {};

    auto stage = [&](int buf, int t) {
        int k0 = t * 32;
        gld16(Ag0 + k0, &As[buf][la0]);
        gld16(Ag1 + k0, &As[buf][la1]);
        gld16(Bg0 + k0, &Bs[buf][la0]);
        gld16(Bg1 + k0, &Bs[buf][la1]);
    };

    stage(0, 0);
    stage(1, 1);

    for (int t = 0; t < 32; ++t) {
        if (t < 30) asm volatile("s_waitcnt vmcnt(4)" ::: "memory");
        else        asm volatile("s_waitcnt vmcnt(0)" ::: "memory");
        __builtin_amdgcn_s_barrier();
        if (t + 2 < 32) stage((t + 2) % 3, t + 2);
        int cur = t % 3;
        bf16x8 af[4], bfr[4];
        #pragma unroll
        for (int i = 0; i < 4; ++i)
            af[i] = *(const bf16x8*)&As[cur][(wm + i * 16 + l16) * 32 + (quad ^ rsw) * 8];
        #pragma unroll
        for (int j = 0; j < 4; ++j)
            bfr[j] = *(const bf16x8*)&Bs[cur][(wn + j * 16 + l16) * 32 + (quad ^ rsw) * 8];
        #pragma unroll
        for (int i = 0; i < 4; ++i)
          #pragma unroll
          for (int j = 0; j < 4; ++j)
            acc[i][j] = __builtin_amdgcn_mfma_f32_16x16x32_bf16(af[i], bfr[j], acc[i][j], 0, 0, 0);
    }
    __builtin_amdgcn_s_barrier();

    #pragma unroll
    for (int i = 0; i < 4; ++i)
      #pragma unroll
      for (int j = 0; j < 4; ++j) {
        int col = bn + wn + j * 16 + l16;
        float bias = (col < 1024) ? bq[col] : (col < 2048) ? bk[col - 1024] : bv[col - 2048];
        int qkv = col >> 10, cw = col & 1023;
        int hh = cw >> 6, d = cw & 63;
        int row0 = bm + wm + i * 16 + quad * 4;
        int bb = row0 >> 11, s0 = row0 & 2047;
        if (qkv < 2) {
            float scl = (qkv == 0) ? QSCALE : 1.0f;
            #pragma unroll
            for (int r = 0; r < 4; ++r)
                Qout[(size_t)qkv * PER + (((size_t)bb * H_ + hh) * S_ + s0 + r) * DH_ + d] =
                    (bf16)((acc[i][j][r] + bias) * scl);
        } else {
            bf16x4 pack;
            #pragma unroll
            for (int r = 0; r < 4; ++r) pack[r] = (bf16)(acc[i][j][r] + bias);
            *(bf16x4*)&Vt[(((size_t)bb * H_ + hh) * DH_ + d) * S_ + s0] = pack;
        }
      }
}

// ---------------- output-projection GEMM v2 (round-8): 128x64, 3-buffer + counted vmcnt ----------------
__global__ __launch_bounds__(256) void gemm_proj(
        const bf16* __restrict__ A, const bf16* __restrict__ Bt,
        const float* __restrict__ bias, float* __restrict__ out) {
    __shared__ __align__(16) bf16 As[3][128 * 32];   // 24 KB
    __shared__ __align__(16) bf16 Bs[3][64 * 32];    // 12 KB
    int tid = threadIdx.x, wave = tid >> 6, lane = tid & 63;
    int quad = lane >> 4, l16 = lane & 15;

    int flat = blockIdx.y * 16 + blockIdx.x;          // nwg = 512
    int swz  = (flat & 7) * 64 + (flat >> 3);         // bijective: 512/8 = 64
    int bm = (swz / 16) * 128, bn = (swz % 16) * 64;
    int wm = (wave >> 1) * 64, wn = (wave & 1) * 32;

    int sr = lane >> 2;
    int sc = (((lane & 3) ^ ((sr ^ (sr >> 2)) & 3)) * 8);
    const bf16* Ag0 = A + (size_t)(bm + (wave * 2 + 0) * 16 + sr) * 1024 + sc;
    const bf16* Ag1 = A + (size_t)(bm + (wave * 2 + 1) * 16 + sr) * 1024 + sc;
    const bf16* Bg0 = Bt + (size_t)(bn + wave * 16 + sr) * 1024 + sc;
    int la0 = (wave * 2 + 0) * 512;
    int la1 = (wave * 2 + 1) * 512;
    int lb0 = wave * 512;

    int rsw = (l16 ^ (l16 >> 2)) & 3;

    f32x4 acc[4][2] = {};

    auto stage = [&](int buf, int t) {
        int k0 = t * 32;
        gld16(Ag0 + k0, &As[buf][la0]);
        gld16(Ag1 + k0, &As[buf][la1]);
        gld16(Bg0 + k0, &Bs[buf][lb0]);
    };

    stage(0, 0);
    stage(1, 1);

    for (int t = 0; t < 32; ++t) {
        if (t < 30) asm volatile("s_waitcnt vmcnt(3)" ::: "memory");
        else        asm volatile("s_waitcnt vmcnt(0)" ::: "memory");
        __builtin_amdgcn_s_barrier();
        if (t + 2 < 32) stage((t + 2) % 3, t + 2);
        int cur = t % 3;
        bf16x8 af[4], bfr[2];
        #pragma unroll
        for (int i = 0; i < 4; ++i)
            af[i] = *(const bf16x8*)&As[cur][(wm + i * 16 + l16) * 32 + (quad ^ rsw) * 8];
        #pragma unroll
        for (int j = 0; j < 2; ++j)
            bfr[j] = *(const bf16x8*)&Bs[cur][(wn + j * 16 + l16) * 32 + (quad ^ rsw) * 8];
        #pragma unroll
        for (int i = 0; i < 4; ++i)
          #pragma unroll
          for (int j = 0; j < 2; ++j)
            acc[i][j] = __builtin_amdgcn_mfma_f32_16x16x32_bf16(af[i], bfr[j], acc[i][j], 0, 0, 0);
    }
    __builtin_amdgcn_s_barrier();

    #pragma unroll
    for (int i = 0; i < 4; ++i)
      #pragma unroll
      for (int j = 0; j < 2; ++j) {
        int col = bn + wn + j * 16 + l16;
        float b = bias[col];
        #pragma unroll
        for (int r = 0; r < 4; ++r) {
            int row = bm + wm + i * 16 + quad * 4 + r;
            out[(size_t)row * 1024 + col] = acc[i][j][r] + b;
        }
      }
}

// ---------------- flash attention v15 (round-13 champion): swapped QK^T, packed b64 P-stores ----------------
__global__ __launch_bounds__(256) void flash15(
        const bf16* __restrict__ Q, const bf16* __restrict__ K,
        const bf16* __restrict__ Vt, bf16* __restrict__ O) {
    int bh = blockIdx.x;
    int b = bh >> 4, h = bh & 15;
    int t = 31 - blockIdx.y;             // heavy tiles dispatch first
    int q0 = t * 64;
    int nkt = t + 1;
    int tid = threadIdx.x;
    int wave = tid >> 6, lane = tid & 63;
    int quad = lane >> 4, l16 = lane & 15;
    int lm = l16 & 7;

    __shared__ __align__(16) bf16 Kl[2][64 * 64];   // 16 KB
    __shared__ __align__(16) bf16 Vl[2][64 * 64];   // 16 KB
    __shared__ bf16 P[4][16][72];                   // 9 KB, per-wave private

    const bf16* Qb = Q + (size_t)bh * S_ * DH_;
    const bf16* Kb = K + (size_t)bh * S_ * DH_;
    const bf16* Vb = Vt + (size_t)bh * DH_ * S_;

    bf16x8 qf[2];
    {
        const bf16* qp = Qb + (size_t)(q0 + wave * 16 + l16) * DH_ + quad * 8;
        qf[0] = *(const bf16x8*)(qp);
        qf[1] = *(const bf16x8*)(qp + 32);
    }

    bf16x8 ones;
    #pragma unroll
    for (int j = 0; j < 8; ++j) ones[j] = (l16 == 0) ? (bf16)1.0f : (bf16)0.0f;

    f32x4 oacc[4] = {};
    f32x4 lacc = {};

    int r8 = lane >> 3, c8 = lane & 7;
    int sco = ((c8 ^ r8) * 8);

    auto stage = [&](int buf, int kt) {
        int kv0 = kt * 64;
        #pragma unroll
        for (int g = 0; g < 2; ++g) {
            int row = wave * 16 + g * 8;                       // wave-uniform
            gld16(Kb + (size_t)(kv0 + row + r8) * DH_ + sco, &Kl[buf][row * 64]);
            gld16(Vb + (size_t)(row + r8) * S_ + kv0 + sco,   &Vl[buf][row * 64]);
        }
    };

    stage(0, 0);
    __syncthreads();     // buffer 0 ready

    for (int kt = 0; kt < nkt; ++kt) {
        int buf = kt & 1;
        if (kt + 1 < nkt) stage(buf ^ 1, kt + 1);   // async prefetch next chunk
        int kv0 = kt * 64;

        bf16x8 kf[4][2];
        #pragma unroll
        for (int ns = 0; ns < 4; ++ns) {
            int row = ns * 16 + l16;
            kf[ns][0] = *(const bf16x8*)&Kl[buf][row * 64 + ((quad)     ^ lm) * 8];
            kf[ns][1] = *(const bf16x8*)&Kl[buf][row * 64 + ((4 + quad) ^ lm) * 8];
        }

        // swapped QK^T (flash6-verified): sacc[ns][r] = S[q=l16][kv=kv0+ns*16+quad*4+r]
        f32x4 sacc[4] = {};
        #pragma unroll
        for (int ns = 0; ns < 4; ++ns) {
            sacc[ns] = __builtin_amdgcn_mfma_f32_16x16x32_bf16(kf[ns][0], qf[0], sacc[ns], 0, 0, 0);
            sacc[ns] = __builtin_amdgcn_mfma_f32_16x16x32_bf16(kf[ns][1], qf[1], sacc[ns], 0, 0, 0);
        }

        bool diag = (kt == nkt - 1);
        #pragma unroll
        for (int ns = 0; ns < 4; ++ns) {
            bf16x4 pk;
            #pragma unroll
            for (int r = 0; r < 4; ++r) {
                float p = __builtin_amdgcn_exp2f(sacc[ns][r]);
                if (diag) {
                    int kv = kv0 + ns * 16 + quad * 4 + r;
                    int qq = q0 + wave * 16 + l16;
                    if (kv > qq) p = 0.f;
                }
                pk[r] = (bf16)p;
            }
            *(bf16x4*)&P[wave][l16][ns * 16 + quad * 4] = pk;
        }

        #pragma unroll
        for (int ks = 0; ks < 2; ++ks) {
            bf16x8 pf = *(const bf16x8*)&P[wave][l16][ks * 32 + quad * 8];
            lacc = __builtin_amdgcn_mfma_f32_16x16x32_bf16(pf, ones, lacc, 0, 0, 0);
            #pragma unroll
            for (int ds = 0; ds < 4; ++ds) {
                bf16x8 vf = *(const bf16x8*)&Vl[buf][(ds * 16 + l16) * 64 + ((ks * 4 + quad) ^ lm) * 8];
                oacc[ds] = __builtin_amdgcn_mfma_f32_16x16x32_bf16(pf, vf, oacc[ds], 0, 0, 0);
            }
        }

        __syncthreads();   // next buffer staged (vmcnt drained) + all waves done with buf
    }

    float ls[4];
    #pragma unroll
    for (int r = 0; r < 4; ++r) ls[r] = __shfl(lacc[r], quad << 4);
    #pragma unroll
    for (int ds = 0; ds < 4; ++ds)
      #pragma unroll
      for (int r = 0; r < 4; ++r) {
          int qq = q0 + wave * 16 + quad * 4 + r;
          O[((size_t)b * S_ + qq) * NDH + h * DH_ + ds * 16 + l16] = (bf16)(oacc[ds][r] / ls[r]);
      }
}

extern "C" void kernel_launch(void* const* d_in, const int* in_sizes, int n_in,
                              void* d_out, int out_size, void* d_ws, size_t ws_size,
                              hipStream_t stream) {
    const float* x  = (const float*)d_in[0];
    const float* Wq = (const float*)d_in[1];
    const float* bq = (const float*)d_in[2];
    const float* Wk = (const float*)d_in[3];
    const float* bk = (const float*)d_in[4];
    const float* Wv = (const float*)d_in[5];
    const float* bv = (const float*)d_in[6];
    const float* Wo = (const float*)d_in[7];
    const float* bo = (const float*)d_in[8];
    float* out = (float*)d_out;

    bf16* ws = (bf16*)d_ws;
    const size_t M1 = (size_t)1024 * 1024;
    bf16* xb    = ws;                   // 4M
    bf16* WqkvT = ws + 4 * M1;          // 3M contiguous (WqT|WkT|WvT)
    bf16* WoT   = ws + 7 * M1;          // 1M
    bf16* Qw    = ws + 8 * M1;          // Q|K contiguous, 4M each
    bf16* Vtw   = ws + 16 * M1;         // 4M ([bh][d][s])
    bf16* Ow    = ws + 20 * M1;         // 4M

    prep<<<6144, 256, 0, stream>>>(x, Wq, Wk, Wv, Wo,
                                   xb, WqkvT, WqkvT + M1, WqkvT + 2 * M1, WoT);

    qkv_gemm<<<dim3(3072 / 128, BS_ / 128), 256, 0, stream>>>(xb, WqkvT, bq, bk, bv, Qw, Vtw);

    flash15<<<dim3(B_ * H_, 32), 256, 0, stream>>>(Qw, Qw + PER, Vtw, Ow);

    gemm_proj<<<dim3(1024 / 64, BS_ / 128), 256, 0, stream>>>(Ow, WoT, bo, out);
}